// Round 16
// baseline (279.083 us; speedup 1.0000x reference)
//
#include <hip/hip_runtime.h>
#include <math.h>

#define Bc 8
#define Nc 1024
#define Dc 1024
#define Hc 16
#define DHc 64
#define NEGINF -1e9f
#define LOG2E 1.44269504f

typedef unsigned int  u32;
typedef unsigned short u16;
typedef unsigned long long u64;
typedef u16  u16x8 __attribute__((ext_vector_type(8)));
typedef u16  u16x4 __attribute__((ext_vector_type(4)));
typedef u32  u32x2 __attribute__((ext_vector_type(2)));
typedef int  i32x4 __attribute__((ext_vector_type(4)));
typedef __bf16 bf16x8 __attribute__((ext_vector_type(8)));
typedef float f32x4 __attribute__((ext_vector_type(4)));

__device__ __forceinline__ u16 f2bf(float f) {           // RTNE float->bf16
    u32 u = __builtin_bit_cast(u32, f);
    u += 0x7fffu + ((u >> 16) & 1u);
    return (u16)(u >> 16);
}
__device__ __forceinline__ float bf2f(u16 b) {
    return __builtin_bit_cast(float, (u32)b << 16);
}
// pack two floats' top halves (truncating bf16) into one u32: low16=lo, high16=hi
__device__ __forceinline__ u32 pack2bf(float lo, float hi) {
    return __builtin_amdgcn_perm(__builtin_bit_cast(u32, hi),
                                 __builtin_bit_cast(u32, lo), 0x07060302u);
}
// raw 2^x (v_exp_f32)
__device__ __forceinline__ float exp2_raw(float x) {
    float r;
    asm("v_exp_f32 %0, %1" : "=v"(r) : "v"(x));
    return r;
}

// async global->LDS, 16 B per lane; LDS dest = wave-uniform base + lane*16.
__device__ __forceinline__ void glds16(const u16* g, const u16* l) {
    __builtin_amdgcn_global_load_lds(
        (const __attribute__((address_space(1))) void*)(u64)g,
        (__attribute__((address_space(3))) void*)(u32)(u64)l, 16, 0, 0);
}

// ---------------------------------------------------------------------------
// prep1: ONLY the true qkv dependencies (bias moved into the qkv dispatch).
//  blocks [0, 4096):     hid fp32 -> bf16
//  blocks [4096, 7168):  W -> W^T bf16 (z = q/k/v)
// ---------------------------------------------------------------------------
__global__ __launch_bounds__(256) void prep1(
    const float* __restrict__ hid, u16* __restrict__ hidb,
    const float* __restrict__ Wq, const float* __restrict__ Wk,
    const float* __restrict__ Wv, u16* __restrict__ WqT,
    u16* __restrict__ WkT, u16* __restrict__ WvT)
{
    const int blk = blockIdx.x;
    const int t = threadIdx.x;

    if (blk < 4096) {
        int idx = blk * 256 + t;               // per 8 elements
        float4 a = ((const float4*)hid)[2 * idx];
        float4 b = ((const float4*)hid)[2 * idx + 1];
        u16x8 o;
        o[0] = f2bf(a.x); o[1] = f2bf(a.y); o[2] = f2bf(a.z); o[3] = f2bf(a.w);
        o[4] = f2bf(b.x); o[5] = f2bf(b.y); o[6] = f2bf(b.z); o[7] = f2bf(b.w);
        ((u16x8*)hidb)[idx] = o;
    } else {
        __shared__ float tile[32][33];
        const int wb = blk - 4096;
        const int x = wb & 31, y = (wb >> 5) & 31, z = wb >> 10;
        const float* W; u16* WT;
        if (z == 0)      { W = Wq; WT = WqT; }
        else if (z == 1) { W = Wk; WT = WkT; }
        else             { W = Wv; WT = WvT; }
        const int tx = t & 31, ty = t >> 5;    // (32, 8)
        const int n0 = x * 32, k0 = y * 32;
#pragma unroll
        for (int i = 0; i < 4; ++i) {
            int r = ty + i * 8;
            tile[r][tx] = W[(size_t)(k0 + r) * Dc + n0 + tx];
        }
        __syncthreads();
#pragma unroll
        for (int i = 0; i < 4; ++i) {
            int n = ty + i * 8;
            WT[(size_t)(n0 + n) * Dc + k0 + tx] = f2bf(tile[tx][n]);
        }
    }
}

// ---------------------------------------------------------------------------
// Kernel 1 (r7): QKV projection MERGED with the independent bias pre-pass.
// Rationale: bias (64 MB adj/relpos reads -> 16 MB bf16 bias) has NO data
// dependency on qkv, and qkv leaves HBM 81% idle (18.7% peak, r7 counters).
// Running bias blocks co-resident with qkv blocks fills qkv's latency
// bubbles with memory work instead of paying a serialized ~15 us pass.
// Grid (64, 56): y%7 < 3  -> qkv slice by = (y/7)*3 + y%7  (24 slices,
//                           IDENTICAL code path to r5/r7's validated qkv;
//                           row-panel = x, XCD = x%8 preserved since
//                           linear id % 8 = x % 8)
//               y%7 >= 3 -> bias block bid = ((y/7)*4 + y%7-3)*64 + x
//                           (2048 blocks, identical validated r5 bias code;
//                           8-entry table parked in As[0..7])
// Interleaved y-pattern (4:3) mixes the two block types in dispatch order.
// ---------------------------------------------------------------------------
__global__ __launch_bounds__(256) void qkv_bias_mfma(
    const u16* __restrict__ hidb, const u16* __restrict__ WqT,
    const u16* __restrict__ WkT, const u16* __restrict__ WvT,
    u16* __restrict__ qo, u16* __restrict__ ko, u16* __restrict__ vo,
    const int* __restrict__ adj, const int* __restrict__ relpos,
    const float* __restrict__ rel_table, u16* __restrict__ bias)
{
    __shared__ u16 As[128 * 64];
    __shared__ u16 Bs[128 * 64];

    const int t = threadIdx.x;
    const int ym = blockIdx.y % 7;
    const int yg = blockIdx.y / 7;           // 0..7

    if (ym >= 3) {
        // ---------------- bias branch (validated r5 code) ----------------
        const int bid = (yg * 4 + (ym - 3)) * 64 + blockIdx.x;   // 0..2047
        if (t < 8) {
            float v = (t < 6) ? rel_table[t] * LOG2E : NEGINF;
            As[t] = f2bf(v);
        }
        __syncthreads();
        const int gid = bid * 256 + t;
        const int o16 = gid << 4;              // base output u16 index
        const int row = o16 >> 10;             // b*N + q
        const int p0  = o16 & 1023;
        const int blkb = p0 & ~63;
        const int tt  = (p0 >> 4) & 3;
        const size_t base = ((size_t)row << 10) + blkb + 4 * tt;
        i32x4 a4[4], r4[4];
#pragma unroll
        for (int u = 0; u < 4; ++u) {
            a4[u] = *(const i32x4*)&adj[base + 16 * u];
            r4[u] = *(const i32x4*)&relpos[base + 16 * u];
        }
        u16x8 o0, o1;
#pragma unroll
        for (int s = 0; s < 8; ++s) {
            const int u = s & 3, e = s >> 2;
            o0[s] = As[a4[u][e] ? r4[u][e] : 6];
        }
#pragma unroll
        for (int s = 8; s < 16; ++s) {
            const int u = s & 3, e = s >> 2;
            o1[s - 8] = As[a4[u][e] ? r4[u][e] : 6];
        }
        *(u16x8*)&bias[(size_t)o16]     = o0;
        *(u16x8*)&bias[(size_t)o16 + 8] = o1;
        return;
    }

    // ---------------- qkv branch (identical to r5/r7 validated) ----------
    const int by = yg * 3 + ym;               // 0..23
    const int z = by >> 3;
    const int c0 = (by & 7) << 7;             // within-z col base
    const int row0 = blockIdx.x << 7;         // global row base (b*N + n)
    const u16* WT; u16* out;
    if (z == 0)      { WT = WqT; out = qo; }
    else if (z == 1) { WT = WkT; out = ko; }
    else             { WT = WvT; out = vo; }
    const float qsc = (z == 0) ? 0.03125f : 1.0f;   // fold 1/sqrt(D) into Q

    const int tid = t;
    const int wave = tid >> 6, lane = tid & 63;
    const int g = lane >> 4, li = lane & 15;
    const int wr = wave >> 1, wc = wave & 1;
    const int lr = lane >> 3, ls = lane & 7;  // staging: row-in-group, seg
    const int sseg = ls ^ lr;                 // swizzled k-segment to fetch

    const u16* pa = hidb + (size_t)(row0 + wave * 32 + lr) * Dc + sseg * 8;
    const u16* pb = WT   + (size_t)(c0   + wave * 32 + lr) * Dc + sseg * 8;
    u16* la = &As[(wave * 32) * 64];
    u16* lb = &Bs[(wave * 32) * 64];

    f32x4 acc[4][4] = {};

    const int swz = (li & 7);                 // fragment-read swizzle key

    for (int kt = 0; kt < Dc; kt += 64) {
        __syncthreads();
#pragma unroll
        for (int i = 0; i < 4; ++i) {
            glds16(pa + kt + i * 8 * Dc, la + i * 8 * 64);
            glds16(pb + kt + i * 8 * Dc, lb + i * 8 * 64);
        }
        __syncthreads();
#pragma unroll
        for (int ks = 0; ks < 2; ++ks) {
            const int soff = ((ks * 4 + g) ^ swz) * 8;
            bf16x8 af[4], bf[4];
#pragma unroll
            for (int mi = 0; mi < 4; ++mi)
                af[mi] = *(const bf16x8*)&As[(wr * 64 + mi * 16 + li) * 64 + soff];
#pragma unroll
            for (int nj = 0; nj < 4; ++nj)
                bf[nj] = *(const bf16x8*)&Bs[(wc * 64 + nj * 16 + li) * 64 + soff];
#pragma unroll
            for (int mi = 0; mi < 4; ++mi)
#pragma unroll
                for (int nj = 0; nj < 4; ++nj)
                    acc[mi][nj] = __builtin_amdgcn_mfma_f32_16x16x32_bf16(
                        af[mi], bf[nj], acc[mi][nj], 0, 0, 0);
        }
    }

    const int b = row0 >> 10;

    if (z != 2) {
        // sigma-d epilogue: lane's 4 cols {li,li+16,li+32,li+48} -> sigma
        // positions 4*li..4*li+3 (contiguous): one b64 RTNE store per (mi,rr)
        const int h2 = (c0 + wc * 64) >> 6;
        const int nbase = (row0 & 1023) + wr * 64 + g * 4;
#pragma unroll
        for (int mi = 0; mi < 4; ++mi)
#pragma unroll
            for (int rr = 0; rr < 4; ++rr) {
                int n = nbase + mi * 16 + rr;
                u32x2 pk;
                pk.x = (u32)f2bf(acc[mi][0][rr] * qsc) | ((u32)f2bf(acc[mi][1][rr] * qsc) << 16);
                pk.y = (u32)f2bf(acc[mi][2][rr] * qsc) | ((u32)f2bf(acc[mi][3][rr] * qsc) << 16);
                *(u32x2*)(out + ((size_t)(b * Hc + h2) * Nc + n) * DHc + 4 * li) = pk;
            }
    } else {
        // per-wave 64x64 transpose in LDS scratch; key dim stored in
        // sigma-permuted order with the usual XOR seg swizzle.
        __syncthreads();
        u16* T = ((wave & 2) ? Bs : As) + (wave & 1) * 4096;
#pragma unroll
        for (int mi = 0; mi < 4; ++mi)
#pragma unroll
            for (int rr = 0; rr < 4; ++rr) {
                int r = mi * 16 + g * 4 + rr;
                int pp = ((r & 15) << 2) | (r >> 4);     // sigma(r)
#pragma unroll
                for (int nj = 0; nj < 4; ++nj) {
                    int c = nj * 16 + li;
                    T[c * 64 + ((((pp >> 3) ^ (c & 7)) << 3) | (pp & 7))]
                        = f2bf(acc[mi][nj][rr]);
                }
            }
        const int nseg = ls ^ lr;
#pragma unroll
        for (int i = 0; i < 8; ++i) {
            int cl = i * 8 + lr;              // local col (d)
            u16x8 val = *(const u16x8*)&T[cl * 64 + ls * 8];
            int cz = c0 + wc * 64 + cl;
            int n = (row0 & 1023) + wr * 64 + nseg * 8;
            *(u16x8*)&vo[(((size_t)(b * Hc + (cz >> 6)) * DHc + (cz & 63)) * Nc) + n] = val;
        }
    }
}

// ---------------------------------------------------------------------------
// Kernel 2: flash attention v5 — single-barrier schedule (validated r5/r7).
// K AND V double-buffered (32 KB); all tile-(it+1) glds + bias prefetch
// issue right after the single barrier; drain at the next barrier (full
// compute phase of cover). PQ 16 KB via XOR swizzle (0 bank conflicts).
// exp2 softmax w/ log2e-premul bias. Fixed-max softmax (max==0 safe);
// q pre-scaled by 1/32 in qkv. XCD swizzle: batch element b on XCD (id&7).
// ---------------------------------------------------------------------------
__global__ __launch_bounds__(256, 3) void attn_mfma(
    const u16* __restrict__ q, const u16* __restrict__ k,
    const u16* __restrict__ v, const u16* __restrict__ bias,
    float* __restrict__ attn_out)
{
    __shared__ u16 Ks[2][64 * 64];    // 16 KB [buf][key][kseg^(key&7)]
    __shared__ u16 VTs[2][64 * 64];   // 16 KB [buf][d][pkseg^(d&7)]
    __shared__ u16 PQ[128 * 64];      // 16 KB Q then P, XOR-swizzled rows

    const int tid = threadIdx.x;
    const int w = tid >> 6, lane = tid & 63;
    const int g = lane >> 4, li = lane & 15;
    const int lr8 = lane >> 3, ls8 = lane & 7;
    const int lseg = ls8 ^ lr8;               // swizzled staging k-seg

    // XCD-locality remap: whole batch element b on XCD (id & 7); h fastest.
    const int id = blockIdx.x;
    const int b  = id & 7;
    const int r_ = id >> 3;                   // 0..127
    const int h  = r_ & 15;
    const int qt = r_ >> 4;
    const int q0 = qt << 7;

    const u16* kbase = k + (size_t)(b * Hc + h) * Nc * DHc;
    const u16* vbase = v + (size_t)(b * Hc + h) * DHc * Nc;
    const u16* brow  = bias + ((size_t)(b * Nc) + q0 + w * 32) * Nc + 4 * li;

    // ---- prologue: issue tile-0 K+V staging first (overlap with Q setup) ----
    {
        const u16* kp = kbase + (size_t)(w * 16 + lr8) * DHc + lseg * 8;
        const u16* vp = vbase + (size_t)(w * 16 + lr8) * Nc + lseg * 8;
        glds16(kp,           &Ks[0][(w * 16) * 64]);
        glds16(kp + 8 * DHc, &Ks[0][(w * 16) * 64 + 8 * 64]);
        glds16(vp,           &VTs[0][(w * 16) * 64]);
        glds16(vp + 8 * Nc,  &VTs[0][(w * 16) * 64 + 8 * 64]);
    }

    // ---- stage Q [128][64] into PQ, swizzled (wave-private rows) ----
    {
        const int sr = tid >> 1;
        const int sh = (tid & 1) * 32;
        const int sw = (sr & 7) << 3;
        const u16* qp = q + ((size_t)((b * Hc + h) * Nc) + q0 + sr) * DHc + sh;
        u16* dst = &PQ[sr * 64];
        *(u16x8*)(dst + ((sh +  0) ^ sw)) = *(const u16x8*)(qp);
        *(u16x8*)(dst + ((sh +  8) ^ sw)) = *(const u16x8*)(qp + 8);
        *(u16x8*)(dst + ((sh + 16) ^ sw)) = *(const u16x8*)(qp + 16);
        *(u16x8*)(dst + ((sh + 24) ^ sw)) = *(const u16x8*)(qp + 24);
    }

    // bias tile 0 prefetch
    u16x4 brv[2][4];
#pragma unroll
    for (int mt = 0; mt < 2; ++mt)
#pragma unroll
        for (int r = 0; r < 4; ++r)
            brv[mt][r] = *(const u16x4*)&brow[(size_t)(mt * 16 + g * 4 + r) * Nc];

    // Q fragments (intra-wave LDS dependency only)
    bf16x8 qf[2][2];
#pragma unroll
    for (int mt = 0; mt < 2; ++mt)
#pragma unroll
        for (int ks = 0; ks < 2; ++ks)
            qf[mt][ks] = *(const bf16x8*)&PQ[(w * 32 + mt * 16 + li) * 64
                                            + ((ks * 32 + g * 8) ^ ((li & 7) << 3))];

    f32x4 o_[2][4] = {};
    float lsum[2][4] = {};

    for (int it = 0; it < 16; ++it) {
        const int cur = it & 1;
        __syncthreads();   // drains K[it]+V[it] glds (full-phase-old); syncs bufs

        u16x4 brn[2][4];
        if (it < 15) {     // issue tile it+1 staging into the other buffer
            const int k1 = (it + 1) * 64;
            const u16* kp = kbase + (size_t)(k1 + w * 16 + lr8) * DHc + lseg * 8;
            const u16* vp = vbase + (size_t)(w * 16 + lr8) * Nc + k1 + lseg * 8;
            u16* kl = &Ks[cur ^ 1][(w * 16) * 64];
            u16* vl = &VTs[cur ^ 1][(w * 16) * 64];
            glds16(kp,           kl);
            glds16(kp + 8 * DHc, kl + 8 * 64);
            glds16(vp,           vl);
            glds16(vp + 8 * Nc,  vl + 8 * 64);
#pragma unroll
            for (int mt = 0; mt < 2; ++mt)
#pragma unroll
                for (int r = 0; r < 4; ++r)
                    brn[mt][r] = *(const u16x4*)&brow[(size_t)(mt * 16 + g * 4 + r) * Nc + k1];
        }

        // --- S = Q.K^T : 16 MFMA, 8 K-frag b128 reads ---
        f32x4 sacc[2][4] = {};
        __builtin_amdgcn_s_setprio(1);
#pragma unroll
        for (int ks = 0; ks < 2; ++ks) {
            const int so = (((ks << 2) | g) ^ (li & 7)) << 3;
#pragma unroll
            for (int nt = 0; nt < 4; ++nt) {
                bf16x8 kf = *(const bf16x8*)&Ks[cur][(nt * 16 + li) * 64 + so];
                sacc[0][nt] = __builtin_amdgcn_mfma_f32_16x16x32_bf16(qf[0][ks], kf, sacc[0][nt], 0, 0, 0);
                sacc[1][nt] = __builtin_amdgcn_mfma_f32_16x16x32_bf16(qf[1][ks], kf, sacc[1][nt], 0, 0, 0);
            }
        }
        __builtin_amdgcn_s_setprio(0);

        // --- softmax: P = 2^(fma(s, log2e, bias2)); packed b64 in sigma-space
        //     (PQ rows are wave-private: no barrier between P write and read)
#pragma unroll
        for (int mt = 0; mt < 2; ++mt)
#pragma unroll
            for (int r = 0; r < 4; ++r) {
                const int qrl = w * 32 + mt * 16 + g * 4 + r;
                float pv[4];
#pragma unroll
                for (int nt = 0; nt < 4; ++nt) {
                    pv[nt] = exp2_raw(fmaf(sacc[mt][nt][r], LOG2E,
                                           bf2f(brv[mt][r][nt])));
                    lsum[mt][r] += pv[nt];
                }
                u32* dst = (u32*)&PQ[(qrl & ~7) * 64
                                     + (((qrl & 7) * 64 + li * 4) ^ ((qrl & 7) << 3))];
                dst[0] = pack2bf(pv[0], pv[1]);
                dst[1] = pack2bf(pv[2], pv[3]);
            }

        // --- O += P.V : 16 MFMA, 4 P-frag + 8 VT-frag b128 reads ---
        __builtin_amdgcn_s_setprio(1);
#pragma unroll
        for (int ks = 0; ks < 2; ++ks) {
            const int so = (((ks << 2) | g) ^ (li & 7)) << 3;
            const int po = (ks * 32 + g * 8) ^ ((li & 7) << 3);
            bf16x8 pa0 = *(const bf16x8*)&PQ[(w * 32 + li) * 64 + po];
            bf16x8 pa1 = *(const bf16x8*)&PQ[(w * 32 + 16 + li) * 64 + po];
#pragma unroll
            for (int j = 0; j < 4; ++j) {
                bf16x8 vf = *(const bf16x8*)&VTs[cur][(j * 16 + li) * 64 + so];
                o_[0][j] = __builtin_amdgcn_mfma_f32_16x16x32_bf16(pa0, vf, o_[0][j], 0, 0, 0);
                o_[1][j] = __builtin_amdgcn_mfma_f32_16x16x32_bf16(pa1, vf, o_[1][j], 0, 0, 0);
            }
        }
        __builtin_amdgcn_s_setprio(0);

        if (it < 15) {
#pragma unroll
            for (int mt = 0; mt < 2; ++mt)
#pragma unroll
                for (int r = 0; r < 4; ++r)
                    brv[mt][r] = brn[mt][r];
        }
    }

    // --- epilogue: reduce row sums across 16 li lanes, normalize, write ---
#pragma unroll
    for (int mt = 0; mt < 2; ++mt)
#pragma unroll
        for (int r = 0; r < 4; ++r) {
            float l = lsum[mt][r];
            l += __shfl_xor(l, 1);
            l += __shfl_xor(l, 2);
            l += __shfl_xor(l, 4);
            l += __shfl_xor(l, 8);
            float inv = 1.f / l;
            int qrow = q0 + w * 32 + mt * 16 + g * 4 + r;
            float* op = attn_out + ((size_t)b * Nc + qrow) * Dc + h * DHc;
#pragma unroll
            for (int j = 0; j < 4; ++j)
                op[j * 16 + li] = o_[mt][j][r] * inv;
        }
}

// ---------------------------------------------------------------------------
// Kernel 3: out = LayerNorm(relu(attn_out) + hid), in-place safe.
// One WAVE per row; 16 floats/lane, pure shuffle reduce, no LDS, no barriers.
// ---------------------------------------------------------------------------
__global__ __launch_bounds__(256) void ln_kernel(
    const float* attn_out, const float* __restrict__ hid,
    const float* __restrict__ gamma, const float* __restrict__ beta,
    float* out)
{
    const int row  = blockIdx.x * 4 + (threadIdx.x >> 6);
    const int lane = threadIdx.x & 63;
    const float* ap = attn_out + (size_t)row * Dc;
    const float* hp = hid + (size_t)row * Dc;

    float4 x[4];
    float s1 = 0.f, s2 = 0.f;
#pragma unroll
    for (int j = 0; j < 4; ++j) {
        const int c = 4 * (lane + 64 * j);
        float4 a = *(const float4*)&ap[c];
        float4 h = *(const float4*)&hp[c];
        x[j].x = fmaxf(a.x, 0.f) + h.x;
        x[j].y = fmaxf(a.y, 0.f) + h.y;
        x[j].z = fmaxf(a.z, 0.f) + h.z;
        x[j].w = fmaxf(a.w, 0.f) + h.w;
        s1 += x[j].x + x[j].y + x[j].z + x[j].w;
        s2 += x[j].x * x[j].x + x[j].y * x[j].y
            + x[j].z * x[j].z + x[j].w * x[j].w;
    }
#pragma unroll
    for (int off = 1; off < 64; off <<= 1) {
        s1 += __shfl_xor(s1, off);
        s2 += __shfl_xor(s2, off);
    }

    float mu  = s1 * (1.f / 1024.f);
    float var = s2 * (1.f / 1024.f) - mu * mu;
    float rstd = rsqrtf(var + 1e-5f);

#pragma unroll
    for (int j = 0; j < 4; ++j) {
        const int c = 4 * (lane + 64 * j);
        float4 g  = *(const float4*)&gamma[c];
        float4 be = *(const float4*)&beta[c];
        float4 r4;
        r4.x = (x[j].x - mu) * rstd * g.x + be.x;
        r4.y = (x[j].y - mu) * rstd * g.y + be.y;
        r4.z = (x[j].z - mu) * rstd * g.z + be.z;
        r4.w = (x[j].w - mu) * rstd * g.w + be.w;
        *(float4*)&out[(size_t)row * Dc + c] = r4;
    }
}

extern "C" void kernel_launch(void* const* d_in, const int* in_sizes, int n_in,
                              void* d_out, int out_size, void* d_ws, size_t ws_size,
                              hipStream_t stream) {
    const float* hid       = (const float*)d_in[0];
    const int*   adj       = (const int*)d_in[1];
    const int*   relpos    = (const int*)d_in[2];
    const float* Wq        = (const float*)d_in[3];
    const float* Wk        = (const float*)d_in[4];
    const float* Wv        = (const float*)d_in[5];
    const float* rel_table = (const float*)d_in[6];
    const float* gamma     = (const float*)d_in[7];
    const float* beta      = (const float*)d_in[8];
    float* out = (float*)d_out;

    const size_t per  = (size_t)Bc * Hc * Nc * DHc;  // 8,388,608
    const size_t wsz  = (size_t)Dc * Dc;             // 1,048,576
    u16* qb   = (u16*)d_ws;                // sigma-d, pre-scaled by 1/32
    u16* kb   = qb + per;                  // sigma-d
    u16* vb   = kb + per;                  // [B,H,DH,N] transposed+sigma-key
    u16* bias = vb + per;                  // B*N*N sigma-key-permuted, *log2e
    u16* hidb = bias + (size_t)Bc * Nc * Nc;
    u16* wqT  = hidb + (size_t)Bc * Nc * Dc;
    u16* wkT  = wqT + wsz;
    u16* wvT  = wkT + wsz;
    // total ws: ~90.2 MB

    prep1<<<7168, 256, 0, stream>>>(hid, hidb, Wq, Wk, Wv, wqT, wkT, wvT);
    qkv_bias_mfma<<<dim3(64, 56), 256, 0, stream>>>(
        hidb, wqT, wkT, wvT, qb, kb, vb, adj, relpos, rel_table, bias);
    attn_mfma<<<1024, 256, 0, stream>>>(qb, kb, vb, bias, out);
    ln_kernel<<<2048, 256, 0, stream>>>(out, hid, gamma, beta, out);
}

// Round 17
// 274.713 us; speedup vs baseline: 1.0159x; 1.0159x over previous
//
#include <hip/hip_runtime.h>
#include <math.h>

#define Bc 8
#define Nc 1024
#define Dc 1024
#define Hc 16
#define DHc 64
#define NEGINF -1e9f
#define LOG2E 1.44269504f

typedef unsigned int  u32;
typedef unsigned short u16;
typedef unsigned long long u64;
typedef u16  u16x8 __attribute__((ext_vector_type(8)));
typedef u16  u16x4 __attribute__((ext_vector_type(4)));
typedef u32  u32x2 __attribute__((ext_vector_type(2)));
typedef int  i32x4 __attribute__((ext_vector_type(4)));
typedef __bf16 bf16x8 __attribute__((ext_vector_type(8)));
typedef float f32x4 __attribute__((ext_vector_type(4)));

__device__ __forceinline__ u16 f2bf(float f) {           // RTNE float->bf16
    u32 u = __builtin_bit_cast(u32, f);
    u += 0x7fffu + ((u >> 16) & 1u);
    return (u16)(u >> 16);
}
__device__ __forceinline__ float bf2f(u16 b) {
    return __builtin_bit_cast(float, (u32)b << 16);
}
// pack two floats' top halves (truncating bf16) into one u32: low16=lo, high16=hi
__device__ __forceinline__ u32 pack2bf(float lo, float hi) {
    return __builtin_amdgcn_perm(__builtin_bit_cast(u32, hi),
                                 __builtin_bit_cast(u32, lo), 0x07060302u);
}
// raw 2^x (v_exp_f32)
__device__ __forceinline__ float exp2_raw(float x) {
    float r;
    asm("v_exp_f32 %0, %1" : "=v"(r) : "v"(x));
    return r;
}

// async global->LDS, 16 B per lane; LDS dest = wave-uniform base + lane*16.
__device__ __forceinline__ void glds16(const u16* g, const u16* l) {
    __builtin_amdgcn_global_load_lds(
        (const __attribute__((address_space(1))) void*)(u64)g,
        (__attribute__((address_space(3))) void*)(u32)(u64)l, 16, 0, 0);
}

// ---------------------------------------------------------------------------
// Fused prepasses (r16 lesson: bias lives HERE, among other memory-bound
// blocks — co-scheduling it with the MFMA qkv kernel time-shared block slots
// (1.5-2/CU) instead of overlapping, costing +21 us marginal vs ~13 serial).
//  blocks [0, 2048):     sigma-permuted bias: 16 outputs/thread from 8x int4
//                        loads; table select idx = adj ? rp : 6 (tbl[6] =
//                        bf16(NEGINF)); premultiplied by log2e (exp2 softmax).
//  blocks [2048, 6144):  hid fp32 -> bf16
//  blocks [6144, 9216):  W -> W^T bf16 (z = q/k/v)
// ---------------------------------------------------------------------------
__global__ __launch_bounds__(256) void prep_fused(
    const int* __restrict__ adj, const int* __restrict__ relpos,
    const float* __restrict__ rel_table, u16* __restrict__ bias,
    const float* __restrict__ hid, u16* __restrict__ hidb,
    const float* __restrict__ Wq, const float* __restrict__ Wk,
    const float* __restrict__ Wv, u16* __restrict__ WqT,
    u16* __restrict__ WkT, u16* __restrict__ WvT)
{
    const int blk = blockIdx.x;
    const int t = threadIdx.x;

    if (blk < 2048) {
        __shared__ u16 tblb[8];
        if (t < 8) {
            float v = (t < 6) ? rel_table[t] * LOG2E : NEGINF;
            tblb[t] = f2bf(v);
        }
        __syncthreads();
        const int gid = blk * 256 + t;
        const int o16 = gid << 4;              // base output u16 index
        const int row = o16 >> 10;             // b*N + q
        const int p0  = o16 & 1023;
        const int blkb = p0 & ~63;
        const int tt  = (p0 >> 4) & 3;
        const size_t base = ((size_t)row << 10) + blkb + 4 * tt;
        i32x4 a4[4], r4[4];
#pragma unroll
        for (int u = 0; u < 4; ++u) {
            a4[u] = *(const i32x4*)&adj[base + 16 * u];
            r4[u] = *(const i32x4*)&relpos[base + 16 * u];
        }
        u16x8 o0, o1;
#pragma unroll
        for (int s = 0; s < 8; ++s) {
            const int u = s & 3, e = s >> 2;
            o0[s] = tblb[a4[u][e] ? r4[u][e] : 6];
        }
#pragma unroll
        for (int s = 8; s < 16; ++s) {
            const int u = s & 3, e = s >> 2;
            o1[s - 8] = tblb[a4[u][e] ? r4[u][e] : 6];
        }
        *(u16x8*)&bias[(size_t)o16]     = o0;
        *(u16x8*)&bias[(size_t)o16 + 8] = o1;
    } else if (blk < 6144) {
        int idx = (blk - 2048) * 256 + t;      // per 8 elements
        float4 a = ((const float4*)hid)[2 * idx];
        float4 b = ((const float4*)hid)[2 * idx + 1];
        u16x8 o;
        o[0] = f2bf(a.x); o[1] = f2bf(a.y); o[2] = f2bf(a.z); o[3] = f2bf(a.w);
        o[4] = f2bf(b.x); o[5] = f2bf(b.y); o[6] = f2bf(b.z); o[7] = f2bf(b.w);
        ((u16x8*)hidb)[idx] = o;
    } else {
        __shared__ float tile[32][33];
        const int wb = blk - 6144;
        const int x = wb & 31, y = (wb >> 5) & 31, z = wb >> 10;
        const float* W; u16* WT;
        if (z == 0)      { W = Wq; WT = WqT; }
        else if (z == 1) { W = Wk; WT = WkT; }
        else             { W = Wv; WT = WvT; }
        const int tx = t & 31, ty = t >> 5;    // (32, 8)
        const int n0 = x * 32, k0 = y * 32;
#pragma unroll
        for (int i = 0; i < 4; ++i) {
            int r = ty + i * 8;
            tile[r][tx] = W[(size_t)(k0 + r) * Dc + n0 + tx];
        }
        __syncthreads();
#pragma unroll
        for (int i = 0; i < 4; ++i) {
            int n = ty + i * 8;
            WT[(size_t)(n0 + n) * Dc + k0 + tx] = f2bf(tile[tx][n]);
        }
    }
}

// ---------------------------------------------------------------------------
// Kernel 1: fused QKV projection (m97-structure). Grid (64, 24): x = row-panel
// -> XCD = x%8, so all 24 (z, col-panel) blocks of a row-panel share an XCD:
// hid A-panel fetched once per XCD, L2-hot.
// z = y>>3 selects Q/K/V. Q output PRE-SCALED by 1/32 (exact, power of two).
// q,k out: bf16 [B,H,N,DH], d sigma-permuted per 64-block.
// v out: bf16 [B,H,DH,N], key dim sigma-permuted per 64-block.
// ---------------------------------------------------------------------------
__global__ __launch_bounds__(256) void qkv_mfma(
    const u16* __restrict__ hidb, const u16* __restrict__ WqT,
    const u16* __restrict__ WkT, const u16* __restrict__ WvT,
    u16* __restrict__ qo, u16* __restrict__ ko, u16* __restrict__ vo)
{
    __shared__ u16 As[128 * 64];
    __shared__ u16 Bs[128 * 64];

    const int by = blockIdx.y;
    const int z = by >> 3;
    const int c0 = (by & 7) << 7;             // within-z col base
    const int row0 = blockIdx.x << 7;         // global row base (b*N + n)
    const u16* WT; u16* out;
    if (z == 0)      { WT = WqT; out = qo; }
    else if (z == 1) { WT = WkT; out = ko; }
    else             { WT = WvT; out = vo; }
    const float qsc = (z == 0) ? 0.03125f : 1.0f;   // fold 1/sqrt(D) into Q

    const int tid = threadIdx.x;
    const int wave = tid >> 6, lane = tid & 63;
    const int g = lane >> 4, li = lane & 15;
    const int wr = wave >> 1, wc = wave & 1;
    const int lr = lane >> 3, ls = lane & 7;  // staging: row-in-group, seg
    const int sseg = ls ^ lr;                 // swizzled k-segment to fetch

    const u16* pa = hidb + (size_t)(row0 + wave * 32 + lr) * Dc + sseg * 8;
    const u16* pb = WT   + (size_t)(c0   + wave * 32 + lr) * Dc + sseg * 8;
    u16* la = &As[(wave * 32) * 64];
    u16* lb = &Bs[(wave * 32) * 64];

    f32x4 acc[4][4] = {};

    const int swz = (li & 7);                 // fragment-read swizzle key

    for (int kt = 0; kt < Dc; kt += 64) {
        __syncthreads();
#pragma unroll
        for (int i = 0; i < 4; ++i) {
            glds16(pa + kt + i * 8 * Dc, la + i * 8 * 64);
            glds16(pb + kt + i * 8 * Dc, lb + i * 8 * 64);
        }
        __syncthreads();
#pragma unroll
        for (int ks = 0; ks < 2; ++ks) {
            const int soff = ((ks * 4 + g) ^ swz) * 8;
            bf16x8 af[4], bf[4];
#pragma unroll
            for (int mi = 0; mi < 4; ++mi)
                af[mi] = *(const bf16x8*)&As[(wr * 64 + mi * 16 + li) * 64 + soff];
#pragma unroll
            for (int nj = 0; nj < 4; ++nj)
                bf[nj] = *(const bf16x8*)&Bs[(wc * 64 + nj * 16 + li) * 64 + soff];
#pragma unroll
            for (int mi = 0; mi < 4; ++mi)
#pragma unroll
                for (int nj = 0; nj < 4; ++nj)
                    acc[mi][nj] = __builtin_amdgcn_mfma_f32_16x16x32_bf16(
                        af[mi], bf[nj], acc[mi][nj], 0, 0, 0);
        }
    }

    const int b = row0 >> 10;

    if (z != 2) {
        // sigma-d epilogue: lane's 4 cols {li,li+16,li+32,li+48} -> sigma
        // positions 4*li..4*li+3 (contiguous): one b64 RTNE store per (mi,rr)
        const int h2 = (c0 + wc * 64) >> 6;
        const int nbase = (row0 & 1023) + wr * 64 + g * 4;
#pragma unroll
        for (int mi = 0; mi < 4; ++mi)
#pragma unroll
            for (int rr = 0; rr < 4; ++rr) {
                int n = nbase + mi * 16 + rr;
                u32x2 pk;
                pk.x = (u32)f2bf(acc[mi][0][rr] * qsc) | ((u32)f2bf(acc[mi][1][rr] * qsc) << 16);
                pk.y = (u32)f2bf(acc[mi][2][rr] * qsc) | ((u32)f2bf(acc[mi][3][rr] * qsc) << 16);
                *(u32x2*)(out + ((size_t)(b * Hc + h2) * Nc + n) * DHc + 4 * li) = pk;
            }
    } else {
        // per-wave 64x64 transpose in LDS scratch; key dim stored in
        // sigma-permuted order with the usual XOR seg swizzle.
        __syncthreads();
        u16* T = ((wave & 2) ? Bs : As) + (wave & 1) * 4096;
#pragma unroll
        for (int mi = 0; mi < 4; ++mi)
#pragma unroll
            for (int rr = 0; rr < 4; ++rr) {
                int r = mi * 16 + g * 4 + rr;
                int pp = ((r & 15) << 2) | (r >> 4);     // sigma(r)
#pragma unroll
                for (int nj = 0; nj < 4; ++nj) {
                    int c = nj * 16 + li;
                    T[c * 64 + ((((pp >> 3) ^ (c & 7)) << 3) | (pp & 7))]
                        = f2bf(acc[mi][nj][rr]);
                }
            }
        const int nseg = ls ^ lr;
#pragma unroll
        for (int i = 0; i < 8; ++i) {
            int cl = i * 8 + lr;              // local col (d)
            u16x8 val = *(const u16x8*)&T[cl * 64 + ls * 8];
            int cz = c0 + wc * 64 + cl;
            int n = (row0 & 1023) + wr * 64 + nseg * 8;
            *(u16x8*)&vo[(((size_t)(b * Hc + (cz >> 6)) * DHc + (cz & 63)) * Nc) + n] = val;
        }
    }
}

// ---------------------------------------------------------------------------
// Kernel 2: flash attention v5 — single-barrier schedule (validated r5/r7).
// K AND V double-buffered (32 KB); all tile-(it+1) glds + bias prefetch
// issue right after the single barrier; drain at the next barrier (full
// compute phase of cover). PQ 16 KB via XOR swizzle (0 bank conflicts).
// exp2 softmax w/ log2e-premul bias. Fixed-max softmax (max==0 safe);
// q pre-scaled by 1/32 in qkv. XCD swizzle: batch element b on XCD (id&7).
// ---------------------------------------------------------------------------
__global__ __launch_bounds__(256, 3) void attn_mfma(
    const u16* __restrict__ q, const u16* __restrict__ k,
    const u16* __restrict__ v, const u16* __restrict__ bias,
    float* __restrict__ attn_out)
{
    __shared__ u16 Ks[2][64 * 64];    // 16 KB [buf][key][kseg^(key&7)]
    __shared__ u16 VTs[2][64 * 64];   // 16 KB [buf][d][pkseg^(d&7)]
    __shared__ u16 PQ[128 * 64];      // 16 KB Q then P, XOR-swizzled rows

    const int tid = threadIdx.x;
    const int w = tid >> 6, lane = tid & 63;
    const int g = lane >> 4, li = lane & 15;
    const int lr8 = lane >> 3, ls8 = lane & 7;
    const int lseg = ls8 ^ lr8;               // swizzled staging k-seg

    // XCD-locality remap: whole batch element b on XCD (id & 7); h fastest.
    const int id = blockIdx.x;
    const int b  = id & 7;
    const int r_ = id >> 3;                   // 0..127
    const int h  = r_ & 15;
    const int qt = r_ >> 4;
    const int q0 = qt << 7;

    const u16* kbase = k + (size_t)(b * Hc + h) * Nc * DHc;
    const u16* vbase = v + (size_t)(b * Hc + h) * DHc * Nc;
    const u16* brow  = bias + ((size_t)(b * Nc) + q0 + w * 32) * Nc + 4 * li;

    // ---- prologue: issue tile-0 K+V staging first (overlap with Q setup) ----
    {
        const u16* kp = kbase + (size_t)(w * 16 + lr8) * DHc + lseg * 8;
        const u16* vp = vbase + (size_t)(w * 16 + lr8) * Nc + lseg * 8;
        glds16(kp,           &Ks[0][(w * 16) * 64]);
        glds16(kp + 8 * DHc, &Ks[0][(w * 16) * 64 + 8 * 64]);
        glds16(vp,           &VTs[0][(w * 16) * 64]);
        glds16(vp + 8 * Nc,  &VTs[0][(w * 16) * 64 + 8 * 64]);
    }

    // ---- stage Q [128][64] into PQ, swizzled (wave-private rows) ----
    {
        const int sr = tid >> 1;
        const int sh = (tid & 1) * 32;
        const int sw = (sr & 7) << 3;
        const u16* qp = q + ((size_t)((b * Hc + h) * Nc) + q0 + sr) * DHc + sh;
        u16* dst = &PQ[sr * 64];
        *(u16x8*)(dst + ((sh +  0) ^ sw)) = *(const u16x8*)(qp);
        *(u16x8*)(dst + ((sh +  8) ^ sw)) = *(const u16x8*)(qp + 8);
        *(u16x8*)(dst + ((sh + 16) ^ sw)) = *(const u16x8*)(qp + 16);
        *(u16x8*)(dst + ((sh + 24) ^ sw)) = *(const u16x8*)(qp + 24);
    }

    // bias tile 0 prefetch
    u16x4 brv[2][4];
#pragma unroll
    for (int mt = 0; mt < 2; ++mt)
#pragma unroll
        for (int r = 0; r < 4; ++r)
            brv[mt][r] = *(const u16x4*)&brow[(size_t)(mt * 16 + g * 4 + r) * Nc];

    // Q fragments (intra-wave LDS dependency only)
    bf16x8 qf[2][2];
#pragma unroll
    for (int mt = 0; mt < 2; ++mt)
#pragma unroll
        for (int ks = 0; ks < 2; ++ks)
            qf[mt][ks] = *(const bf16x8*)&PQ[(w * 32 + mt * 16 + li) * 64
                                            + ((ks * 32 + g * 8) ^ ((li & 7) << 3))];

    f32x4 o_[2][4] = {};
    float lsum[2][4] = {};

    for (int it = 0; it < 16; ++it) {
        const int cur = it & 1;
        __syncthreads();   // drains K[it]+V[it] glds (full-phase-old); syncs bufs

        u16x4 brn[2][4];
        if (it < 15) {     // issue tile it+1 staging into the other buffer
            const int k1 = (it + 1) * 64;
            const u16* kp = kbase + (size_t)(k1 + w * 16 + lr8) * DHc + lseg * 8;
            const u16* vp = vbase + (size_t)(w * 16 + lr8) * Nc + k1 + lseg * 8;
            u16* kl = &Ks[cur ^ 1][(w * 16) * 64];
            u16* vl = &VTs[cur ^ 1][(w * 16) * 64];
            glds16(kp,           kl);
            glds16(kp + 8 * DHc, kl + 8 * 64);
            glds16(vp,           vl);
            glds16(vp + 8 * Nc,  vl + 8 * 64);
#pragma unroll
            for (int mt = 0; mt < 2; ++mt)
#pragma unroll
                for (int r = 0; r < 4; ++r)
                    brn[mt][r] = *(const u16x4*)&brow[(size_t)(mt * 16 + g * 4 + r) * Nc + k1];
        }

        // --- S = Q.K^T : 16 MFMA, 8 K-frag b128 reads ---
        f32x4 sacc[2][4] = {};
        __builtin_amdgcn_s_setprio(1);
#pragma unroll
        for (int ks = 0; ks < 2; ++ks) {
            const int so = (((ks << 2) | g) ^ (li & 7)) << 3;
#pragma unroll
            for (int nt = 0; nt < 4; ++nt) {
                bf16x8 kf = *(const bf16x8*)&Ks[cur][(nt * 16 + li) * 64 + so];
                sacc[0][nt] = __builtin_amdgcn_mfma_f32_16x16x32_bf16(qf[0][ks], kf, sacc[0][nt], 0, 0, 0);
                sacc[1][nt] = __builtin_amdgcn_mfma_f32_16x16x32_bf16(qf[1][ks], kf, sacc[1][nt], 0, 0, 0);
            }
        }
        __builtin_amdgcn_s_setprio(0);

        // --- softmax: P = 2^(fma(s, log2e, bias2)); packed b64 in sigma-space
        //     (PQ rows are wave-private: no barrier between P write and read)
#pragma unroll
        for (int mt = 0; mt < 2; ++mt)
#pragma unroll
            for (int r = 0; r < 4; ++r) {
                const int qrl = w * 32 + mt * 16 + g * 4 + r;
                float pv[4];
#pragma unroll
                for (int nt = 0; nt < 4; ++nt) {
                    pv[nt] = exp2_raw(fmaf(sacc[mt][nt][r], LOG2E,
                                           bf2f(brv[mt][r][nt])));
                    lsum[mt][r] += pv[nt];
                }
                u32* dst = (u32*)&PQ[(qrl & ~7) * 64
                                     + (((qrl & 7) * 64 + li * 4) ^ ((qrl & 7) << 3))];
                dst[0] = pack2bf(pv[0], pv[1]);
                dst[1] = pack2bf(pv[2], pv[3]);
            }

        // --- O += P.V : 16 MFMA, 4 P-frag + 8 VT-frag b128 reads ---
        __builtin_amdgcn_s_setprio(1);
#pragma unroll
        for (int ks = 0; ks < 2; ++ks) {
            const int so = (((ks << 2) | g) ^ (li & 7)) << 3;
            const int po = (ks * 32 + g * 8) ^ ((li & 7) << 3);
            bf16x8 pa0 = *(const bf16x8*)&PQ[(w * 32 + li) * 64 + po];
            bf16x8 pa1 = *(const bf16x8*)&PQ[(w * 32 + 16 + li) * 64 + po];
#pragma unroll
            for (int j = 0; j < 4; ++j) {
                bf16x8 vf = *(const bf16x8*)&VTs[cur][(j * 16 + li) * 64 + so];
                o_[0][j] = __builtin_amdgcn_mfma_f32_16x16x32_bf16(pa0, vf, o_[0][j], 0, 0, 0);
                o_[1][j] = __builtin_amdgcn_mfma_f32_16x16x32_bf16(pa1, vf, o_[1][j], 0, 0, 0);
            }
        }
        __builtin_amdgcn_s_setprio(0);

        if (it < 15) {
#pragma unroll
            for (int mt = 0; mt < 2; ++mt)
#pragma unroll
                for (int r = 0; r < 4; ++r)
                    brv[mt][r] = brn[mt][r];
        }
    }

    // --- epilogue: reduce row sums across 16 li lanes, normalize, write ---
#pragma unroll
    for (int mt = 0; mt < 2; ++mt)
#pragma unroll
        for (int r = 0; r < 4; ++r) {
            float l = lsum[mt][r];
            l += __shfl_xor(l, 1);
            l += __shfl_xor(l, 2);
            l += __shfl_xor(l, 4);
            l += __shfl_xor(l, 8);
            float inv = 1.f / l;
            int qrow = q0 + w * 32 + mt * 16 + g * 4 + r;
            float* op = attn_out + ((size_t)b * Nc + qrow) * Dc + h * DHc;
#pragma unroll
            for (int j = 0; j < 4; ++j)
                op[j * 16 + li] = o_[mt][j][r] * inv;
        }
}

// ---------------------------------------------------------------------------
// Kernel 3: out = LayerNorm(relu(attn_out) + hid), in-place safe.
// One WAVE per row; 16 floats/lane, pure shuffle reduce, no LDS, no barriers.
// ---------------------------------------------------------------------------
__global__ __launch_bounds__(256) void ln_kernel(
    const float* attn_out, const float* __restrict__ hid,
    const float* __restrict__ gamma, const float* __restrict__ beta,
    float* out)
{
    const int row  = blockIdx.x * 4 + (threadIdx.x >> 6);
    const int lane = threadIdx.x & 63;
    const float* ap = attn_out + (size_t)row * Dc;
    const float* hp = hid + (size_t)row * Dc;

    float4 x[4];
    float s1 = 0.f, s2 = 0.f;
#pragma unroll
    for (int j = 0; j < 4; ++j) {
        const int c = 4 * (lane + 64 * j);
        float4 a = *(const float4*)&ap[c];
        float4 h = *(const float4*)&hp[c];
        x[j].x = fmaxf(a.x, 0.f) + h.x;
        x[j].y = fmaxf(a.y, 0.f) + h.y;
        x[j].z = fmaxf(a.z, 0.f) + h.z;
        x[j].w = fmaxf(a.w, 0.f) + h.w;
        s1 += x[j].x + x[j].y + x[j].z + x[j].w;
        s2 += x[j].x * x[j].x + x[j].y * x[j].y
            + x[j].z * x[j].z + x[j].w * x[j].w;
    }
#pragma unroll
    for (int off = 1; off < 64; off <<= 1) {
        s1 += __shfl_xor(s1, off);
        s2 += __shfl_xor(s2, off);
    }

    float mu  = s1 * (1.f / 1024.f);
    float var = s2 * (1.f / 1024.f) - mu * mu;
    float rstd = rsqrtf(var + 1e-5f);

#pragma unroll
    for (int j = 0; j < 4; ++j) {
        const int c = 4 * (lane + 64 * j);
        float4 g  = *(const float4*)&gamma[c];
        float4 be = *(const float4*)&beta[c];
        float4 r4;
        r4.x = (x[j].x - mu) * rstd * g.x + be.x;
        r4.y = (x[j].y - mu) * rstd * g.y + be.y;
        r4.z = (x[j].z - mu) * rstd * g.z + be.z;
        r4.w = (x[j].w - mu) * rstd * g.w + be.w;
        *(float4*)&out[(size_t)row * Dc + c] = r4;
    }
}

extern "C" void kernel_launch(void* const* d_in, const int* in_sizes, int n_in,
                              void* d_out, int out_size, void* d_ws, size_t ws_size,
                              hipStream_t stream) {
    const float* hid       = (const float*)d_in[0];
    const int*   adj       = (const int*)d_in[1];
    const int*   relpos    = (const int*)d_in[2];
    const float* Wq        = (const float*)d_in[3];
    const float* Wk        = (const float*)d_in[4];
    const float* Wv        = (const float*)d_in[5];
    const float* rel_table = (const float*)d_in[6];
    const float* gamma     = (const float*)d_in[7];
    const float* beta      = (const float*)d_in[8];
    float* out = (float*)d_out;

    const size_t per  = (size_t)Bc * Hc * Nc * DHc;  // 8,388,608
    const size_t wsz  = (size_t)Dc * Dc;             // 1,048,576
    u16* qb   = (u16*)d_ws;                // sigma-d, pre-scaled by 1/32
    u16* kb   = qb + per;                  // sigma-d
    u16* vb   = kb + per;                  // [B,H,DH,N] transposed+sigma-key
    u16* bias = vb + per;                  // B*N*N sigma-key-permuted, *log2e
    u16* hidb = bias + (size_t)Bc * Nc * Nc;
    u16* wqT  = hidb + (size_t)Bc * Nc * Dc;
    u16* wkT  = wqT + wsz;
    u16* wvT  = wkT + wsz;
    // total ws: ~90.2 MB

    prep_fused<<<9216, 256, 0, stream>>>(adj, relpos, rel_table, bias,
                                         hid, hidb, Wq, Wk, Wv, wqT, wkT, wvT);
    qkv_mfma<<<dim3(64, 24), 256, 0, stream>>>(hidb, wqT, wkT, wvT, qb, kb, vb);
    attn_mfma<<<1024, 256, 0, stream>>>(qb, kb, vb, bias, out);
    ln_kernel<<<2048, 256, 0, stream>>>(out, hid, gamma, beta, out);
}